// Round 1
// baseline (457.297 us; speedup 1.0000x reference)
//
#include <hip/hip_runtime.h>
#include <hip/hip_bf16.h>
#include <cstdint>

#define Bb 2
#define Nc 6
#define Qn 900
#define Cc 256
#define Hc 116
#define Wc 200
#define Pp (Hc * Wc)          // 23200 pixels per (bn) plane
#define EPSf 1e-5f

struct Proj { int x0, y0; float wx, wy; };  // 16 B, x0==INT32_MIN => invalid

// ---------------- Kernel A: project reference points through lidar2img ----------------
__global__ void proj_kernel(const float* __restrict__ ref_pts,   // (B, Q, 3)
                            const float* __restrict__ l2i,       // (B, N, 4, 4)
                            Proj* __restrict__ proj) {           // (B*N, Q)
    int t = blockIdx.x * blockDim.x + threadIdx.x;
    if (t >= Bb * Nc * Qn) return;
    int q  = t % Qn;
    int bn = t / Qn;            // b*Nc + n
    int b  = bn / Nc;

    const float* p = ref_pts + ((size_t)b * Qn + q) * 3;
    float px = p[0], py = p[1], pz = p[2];
    const float* M = l2i + (size_t)bn * 16;
    float h0 = M[0]*px + M[1]*py + M[2]*pz  + M[3];
    float h1 = M[4]*px + M[5]*py + M[6]*pz  + M[7];
    float h2 = M[8]*px + M[9]*py + M[10]*pz + M[11];

    float denom = fabsf(h2) + EPSf;
    float x2d = h0 / denom;
    float y2d = h1 / denom;
    // match reference op order: pts / (W-1) * 2 - 1
    float gx = x2d / (float)(Wc - 1) * 2.0f - 1.0f;
    float gy = y2d / (float)(Hc - 1) * 2.0f - 1.0f;
    bool front = h2 > EPSf;
    bool in_img = fmaxf(fabsf(gx), fabsf(gy)) <= 1.0f;

    Proj o;
    if (front && in_img) {
        // align_corners=False mapping
        float x = ((gx + 1.0f) * (float)Wc - 1.0f) * 0.5f;
        float y = ((gy + 1.0f) * (float)Hc - 1.0f) * 0.5f;
        float x0f = floorf(x), y0f = floorf(y);
        o.x0 = (int)x0f;
        o.y0 = (int)y0f;
        o.wx = x - x0f;
        o.wy = y - y0f;
    } else {
        o.x0 = INT32_MIN; o.y0 = 0; o.wx = 0.0f; o.wy = 0.0f;
    }
    proj[t] = o;
}

// ---------------- Kernel T: transpose (BN, C, P) -> (BN, P, C) ----------------
// 64x64 tiles, float4 on both the global read (along P) and global write (along C).
// LDS padded [64][65]: read phase scalar writes, write phase gathers 4 rows -> 2-way max (free).
__global__ void transpose_kernel(const float* __restrict__ in,   // (BN, C, P)
                                 float* __restrict__ out) {      // (BN, P, C)
    __shared__ float s[64][65];
    int bn = blockIdx.z;
    int c0 = blockIdx.y * 64;
    int p0 = blockIdx.x * 64;
    int tid = threadIdx.x;

    int lp = (tid & 15) * 4;      // pixel offset within tile (read phase)
    int lc = tid >> 4;            // 0..15 channel row, stepped by 16
    const float* src = in + ((size_t)bn * Cc + c0) * Pp + p0;
    bool full = (p0 + 64 <= Pp);  // Pp % 64 == 32, tail tile has 32 valid pixels

    #pragma unroll
    for (int i = 0; i < 4; ++i) {
        int c = lc + i * 16;
        if (full || (lp < Pp - p0)) {   // tail is 32-aligned => float4 fully valid or fully invalid
            float4 v = *(const float4*)(src + (size_t)c * Pp + lp);
            s[c][lp + 0] = v.x; s[c][lp + 1] = v.y;
            s[c][lp + 2] = v.z; s[c][lp + 3] = v.w;
        }
    }
    __syncthreads();

    int wc = (tid & 15) * 4;      // channel offset (write phase)
    int wp = tid >> 4;            // pixel row, stepped by 16
    float* dst = out + ((size_t)bn * Pp + p0) * Cc + c0;
    #pragma unroll
    for (int i = 0; i < 4; ++i) {
        int p = wp + i * 16;
        if (full || (p < Pp - p0)) {
            float4 v = make_float4(s[wc + 0][p], s[wc + 1][p],
                                   s[wc + 2][p], s[wc + 3][p]);
            *(float4*)(dst + (size_t)p * Cc + wc) = v;
        }
    }
}

// ---------------- Kernel B': bilinear gather from channel-last layout ----------------
// block = one (b,q), thread = channel c. All 4 corner loads are fully coalesced
// (64 lanes x 4 B contiguous per wave).
__global__ void sample_kernel_t(const float* __restrict__ featsT,  // (B*N, P, C)
                                const Proj* __restrict__ proj,     // (B*N, Q)
                                float* __restrict__ agg) {         // (B*Q, C)
    int bq = blockIdx.x;            // 0 .. B*Qn-1
    int b  = bq / Qn;
    int q  = bq % Qn;
    int c  = threadIdx.x;           // 0..255

    float acc = 0.0f;
    #pragma unroll
    for (int n = 0; n < Nc; ++n) {
        int bn = b * Nc + n;
        Proj pr = proj[(size_t)bn * Qn + q];       // uniform across block
        if (pr.x0 == INT32_MIN) continue;          // uniform branch

        int x0 = pr.x0, y0 = pr.y0, x1 = x0 + 1, y1 = y0 + 1;
        float wx = pr.wx, wy = pr.wy;

        bool vx0 = (x0 >= 0) & (x0 < Wc);
        bool vx1 = (x1 >= 0) & (x1 < Wc);
        bool vy0 = (y0 >= 0) & (y0 < Hc);
        bool vy1 = (y1 >= 0) & (y1 < Hc);
        int cx0 = min(max(x0, 0), Wc - 1);
        int cx1 = min(max(x1, 0), Wc - 1);
        int cy0 = min(max(y0, 0), Hc - 1);
        int cy1 = min(max(y1, 0), Hc - 1);

        const float* base = featsT + (size_t)bn * Pp * Cc + c;
        float v00 = base[(size_t)(cy0 * Wc + cx0) * Cc] * ((vx0 & vy0) ? 1.0f : 0.0f);
        float v01 = base[(size_t)(cy0 * Wc + cx1) * Cc] * ((vx1 & vy0) ? 1.0f : 0.0f);
        float v10 = base[(size_t)(cy1 * Wc + cx0) * Cc] * ((vx0 & vy1) ? 1.0f : 0.0f);
        float v11 = base[(size_t)(cy1 * Wc + cx1) * Cc] * ((vx1 & vy1) ? 1.0f : 0.0f);

        acc += (v00 * (1.0f - wx) + v01 * wx) * (1.0f - wy)
             + (v10 * (1.0f - wx) + v11 * wx) * wy;
    }
    agg[(size_t)bq * Cc + c] = acc * (1.0f / 6.0f);
}

// ---------------- Kernel B (fallback): gather directly from (BN, C, H, W) ----------------
__global__ void sample_kernel(const float* __restrict__ feats,   // (B*N, C, H, W)
                              const Proj* __restrict__ proj,     // (B*N, Q)
                              float* __restrict__ agg) {         // (B*Q, C)
    int bq = blockIdx.x;
    int b  = bq / Qn;
    int q  = bq % Qn;
    int c  = threadIdx.x;

    float acc = 0.0f;
    #pragma unroll
    for (int n = 0; n < Nc; ++n) {
        int bn = b * Nc + n;
        Proj pr = proj[(size_t)bn * Qn + q];
        if (pr.x0 == INT32_MIN) continue;

        const float* img = feats + ((size_t)bn * Cc + c) * (size_t)Pp;
        int x0 = pr.x0, y0 = pr.y0, x1 = x0 + 1, y1 = y0 + 1;
        float wx = pr.wx, wy = pr.wy;

        bool vx0 = (x0 >= 0) & (x0 < Wc);
        bool vx1 = (x1 >= 0) & (x1 < Wc);
        bool vy0 = (y0 >= 0) & (y0 < Hc);
        bool vy1 = (y1 >= 0) & (y1 < Hc);
        int cx0 = min(max(x0, 0), Wc - 1);
        int cx1 = min(max(x1, 0), Wc - 1);
        int cy0 = min(max(y0, 0), Hc - 1);
        int cy1 = min(max(y1, 0), Hc - 1);

        float v00 = img[cy0 * Wc + cx0] * ((vx0 & vy0) ? 1.0f : 0.0f);
        float v01 = img[cy0 * Wc + cx1] * ((vx1 & vy0) ? 1.0f : 0.0f);
        float v10 = img[cy1 * Wc + cx0] * ((vx0 & vy1) ? 1.0f : 0.0f);
        float v11 = img[cy1 * Wc + cx1] * ((vx1 & vy1) ? 1.0f : 0.0f);

        acc += (v00 * (1.0f - wx) + v01 * wx) * (1.0f - wy)
             + (v10 * (1.0f - wx) + v11 * wx) * wy;
    }
    agg[(size_t)bq * Cc + c] = acc * (1.0f / 6.0f);
}

// ---------------- Kernel C: out = agg @ W_out^T + b_out ----------------
#define QT 8
__global__ void out_gemm(const float* __restrict__ agg,    // (B*Q, C)
                         const float* __restrict__ Wm,     // (C, C) row-major
                         const float* __restrict__ bias,   // (C,)
                         float* __restrict__ out) {        // (B*Q, C)
    __shared__ float sA[QT][Cc];
    int base_q = blockIdx.x * QT;
    int tid = threadIdx.x;          // 0..255 = co

    for (int i = tid; i < QT * Cc; i += 256)
        sA[i / Cc][i % Cc] = agg[(size_t)base_q * Cc + i];
    __syncthreads();

    float acc[QT];
    #pragma unroll
    for (int j = 0; j < QT; ++j) acc[j] = 0.0f;

    const float4* wrow = (const float4*)(Wm + (size_t)tid * Cc);
    #pragma unroll 4
    for (int c4 = 0; c4 < Cc / 4; ++c4) {
        float4 w = wrow[c4];
        #pragma unroll
        for (int j = 0; j < QT; ++j) {
            acc[j] += w.x * sA[j][4*c4 + 0] + w.y * sA[j][4*c4 + 1]
                    + w.z * sA[j][4*c4 + 2] + w.w * sA[j][4*c4 + 3];
        }
    }
    float bb = bias[tid];
    #pragma unroll
    for (int j = 0; j < QT; ++j)
        out[(size_t)(base_q + j) * Cc + tid] = acc[j] + bb;
}

extern "C" void kernel_launch(void* const* d_in, const int* in_sizes, int n_in,
                              void* d_out, int out_size, void* d_ws, size_t ws_size,
                              hipStream_t stream) {
    // inputs: 0=query (unused), 1=reference_points, 2=image_features, 3=lidar2img, 4=W_out, 5=b_out
    const float* ref_pts = (const float*)d_in[1];
    const float* feats   = (const float*)d_in[2];
    const float* l2i     = (const float*)d_in[3];
    const float* Wm      = (const float*)d_in[4];
    const float* bias    = (const float*)d_in[5];
    float* out = (float*)d_out;

    size_t proj_bytes = (size_t)Bb * Nc * Qn * sizeof(Proj);
    proj_bytes = (proj_bytes + 255) & ~(size_t)255;
    size_t agg_bytes = (size_t)Bb * Qn * Cc * sizeof(float);
    agg_bytes = (agg_bytes + 255) & ~(size_t)255;
    size_t featsT_bytes = (size_t)Bb * Nc * Pp * Cc * sizeof(float);

    Proj*  proj = (Proj*)d_ws;
    float* agg  = (float*)((char*)d_ws + proj_bytes);

    int npts = Bb * Nc * Qn;
    proj_kernel<<<(npts + 255) / 256, 256, 0, stream>>>(ref_pts, l2i, proj);

    if (ws_size >= proj_bytes + agg_bytes + featsT_bytes) {
        // channel-last path: coalesced transpose then coalesced gather
        float* featsT = (float*)((char*)d_ws + proj_bytes + agg_bytes);
        dim3 tgrid((Pp + 63) / 64, Cc / 64, Bb * Nc);
        transpose_kernel<<<tgrid, 256, 0, stream>>>(feats, featsT);
        sample_kernel_t<<<Bb * Qn, 256, 0, stream>>>(featsT, proj, agg);
    } else {
        // fallback: direct strided gather (previous behavior)
        sample_kernel<<<Bb * Qn, 256, 0, stream>>>(feats, proj, agg);
    }

    out_gemm<<<(Bb * Qn) / QT, 256, 0, stream>>>(agg, Wm, bias, out);
}

// Round 2
// 379.605 us; speedup vs baseline: 1.2047x; 1.2047x over previous
//
#include <hip/hip_runtime.h>
#include <cstdint>

#define Bb 2
#define Nc 6
#define Qn 900
#define Cc 256
#define Hc 116
#define Wc 200
#define Pp (Hc * Wc)
#define EPSf 1e-5f

struct Proj { int x0, y0; float wx, wy; };  // 16 B, x0==INT32_MIN => invalid

// ---------------- Kernel A: project reference points through lidar2img ----------------
__global__ void proj_kernel(const float* __restrict__ ref_pts,   // (B, Q, 3)
                            const float* __restrict__ l2i,       // (B, N, 4, 4)
                            Proj* __restrict__ proj) {           // (B*N, Q)
    int t = blockIdx.x * blockDim.x + threadIdx.x;
    if (t >= Bb * Nc * Qn) return;
    int q  = t % Qn;
    int bn = t / Qn;            // b*Nc + n
    int b  = bn / Nc;

    const float* p = ref_pts + ((size_t)b * Qn + q) * 3;
    float px = p[0], py = p[1], pz = p[2];
    const float* M = l2i + (size_t)bn * 16;
    float h0 = M[0]*px + M[1]*py + M[2]*pz  + M[3];
    float h1 = M[4]*px + M[5]*py + M[6]*pz  + M[7];
    float h2 = M[8]*px + M[9]*py + M[10]*pz + M[11];

    float denom = fabsf(h2) + EPSf;
    float x2d = h0 / denom;
    float y2d = h1 / denom;
    // match reference op order: pts / (W-1) * 2 - 1
    float gx = x2d / (float)(Wc - 1) * 2.0f - 1.0f;
    float gy = y2d / (float)(Hc - 1) * 2.0f - 1.0f;
    bool front = h2 > EPSf;
    bool in_img = fmaxf(fabsf(gx), fabsf(gy)) <= 1.0f;

    Proj o;
    if (front && in_img) {
        // align_corners=False mapping
        float x = ((gx + 1.0f) * (float)Wc - 1.0f) * 0.5f;
        float y = ((gy + 1.0f) * (float)Hc - 1.0f) * 0.5f;
        float x0f = floorf(x), y0f = floorf(y);
        o.x0 = (int)x0f;
        o.y0 = (int)y0f;
        o.wx = x - x0f;
        o.wy = y - y0f;
    } else {
        o.x0 = INT32_MIN; o.y0 = 0; o.wx = 0.0f; o.wy = 0.0f;
    }
    proj[t] = o;
}

// ---------------- Kernel B: camera-major bilinear gather ----------------
// One block per (bn, q): consecutive block IDs share one camera plane, so the
// concurrently-resident working set is ~2 planes (~50 MB) << 256 MB L3 —
// duplicate channel-line touches hit L3 instead of re-fetching from HBM.
// Writes per-camera partials to samp (B*N*Q, C); mean folded into out_gemm.
__global__ void sample1_kernel(const float* __restrict__ feats,   // (B*N, C, H, W)
                               const Proj* __restrict__ proj,     // (B*N*Q,)
                               float* __restrict__ samp) {        // (B*N*Q, C)
    int blk = blockIdx.x;           // bn*Qn + q
    int c   = threadIdx.x;          // 0..255
    size_t ob = (size_t)blk * Cc + c;

    Proj pr = proj[blk];            // uniform across block -> scalar load
    if (pr.x0 == INT32_MIN) {       // uniform branch
        samp[ob] = 0.0f;
        return;
    }
    int bn = blk / Qn;

    const float* img = feats + ((size_t)bn * Cc + c) * (size_t)Pp;
    int x0 = pr.x0, y0 = pr.y0, x1 = x0 + 1, y1 = y0 + 1;
    float wx = pr.wx, wy = pr.wy;

    bool vx0 = (x0 >= 0) & (x0 < Wc);
    bool vx1 = (x1 >= 0) & (x1 < Wc);
    bool vy0 = (y0 >= 0) & (y0 < Hc);
    bool vy1 = (y1 >= 0) & (y1 < Hc);
    int cx0 = min(max(x0, 0), Wc - 1);
    int cx1 = min(max(x1, 0), Wc - 1);
    int cy0 = min(max(y0, 0), Hc - 1);
    int cy1 = min(max(y1, 0), Hc - 1);

    float v00 = img[cy0 * Wc + cx0] * ((vx0 & vy0) ? 1.0f : 0.0f);
    float v01 = img[cy0 * Wc + cx1] * ((vx1 & vy0) ? 1.0f : 0.0f);
    float v10 = img[cy1 * Wc + cx0] * ((vx0 & vy1) ? 1.0f : 0.0f);
    float v11 = img[cy1 * Wc + cx1] * ((vx1 & vy1) ? 1.0f : 0.0f);

    samp[ob] = (v00 * (1.0f - wx) + v01 * wx) * (1.0f - wy)
             + (v10 * (1.0f - wx) + v11 * wx) * wy;
}

// ---------------- Kernel C: out = mean_n(samp) @ W_out^T + b_out ----------------
// 6-way camera mean folded into the LDS staging loop (coalesced reads).
#define QT 8
__global__ void out_gemm(const float* __restrict__ samp,   // (B*N*Q, C)
                         const float* __restrict__ Wm,     // (C, C) row-major
                         const float* __restrict__ bias,   // (C,)
                         float* __restrict__ out) {        // (B*Q, C)
    __shared__ float sA[QT][Cc];
    int base_q = blockIdx.x * QT;   // row in (B*Q)
    int tid = threadIdx.x;          // 0..255 = co

    for (int i = tid; i < QT * Cc; i += 256) {
        int j = i >> 8;             // Cc == 256
        int c = i & 255;
        int row = base_q + j;
        int b  = row / Qn;
        int qq = row - b * Qn;
        const float* sp = samp + ((size_t)(b * Nc) * Qn + qq) * Cc + c;
        float s = 0.0f;
        #pragma unroll
        for (int n = 0; n < Nc; ++n)
            s += sp[(size_t)n * Qn * Cc];
        sA[j][c] = s * (1.0f / 6.0f);
    }
    __syncthreads();

    float acc[QT];
    #pragma unroll
    for (int j = 0; j < QT; ++j) acc[j] = 0.0f;

    const float4* wrow = (const float4*)(Wm + (size_t)tid * Cc);
    #pragma unroll 4
    for (int c4 = 0; c4 < Cc / 4; ++c4) {
        float4 w = wrow[c4];
        #pragma unroll
        for (int j = 0; j < QT; ++j) {
            acc[j] += w.x * sA[j][4*c4 + 0] + w.y * sA[j][4*c4 + 1]
                    + w.z * sA[j][4*c4 + 2] + w.w * sA[j][4*c4 + 3];
        }
    }
    float bb = bias[tid];
    #pragma unroll
    for (int j = 0; j < QT; ++j)
        out[(size_t)(base_q + j) * Cc + tid] = acc[j] + bb;
}

extern "C" void kernel_launch(void* const* d_in, const int* in_sizes, int n_in,
                              void* d_out, int out_size, void* d_ws, size_t ws_size,
                              hipStream_t stream) {
    // inputs: 0=query (unused), 1=reference_points, 2=image_features, 3=lidar2img, 4=W_out, 5=b_out
    const float* ref_pts = (const float*)d_in[1];
    const float* feats   = (const float*)d_in[2];
    const float* l2i     = (const float*)d_in[3];
    const float* Wm      = (const float*)d_in[4];
    const float* bias    = (const float*)d_in[5];
    float* out = (float*)d_out;

    size_t proj_bytes = (size_t)Bb * Nc * Qn * sizeof(Proj);   // 172,800 B (256-aligned)
    proj_bytes = (proj_bytes + 255) & ~(size_t)255;

    Proj*  proj = (Proj*)d_ws;
    float* samp = (float*)((char*)d_ws + proj_bytes);          // (B*N*Q, C) = 11.06 MB

    int npts = Bb * Nc * Qn;   // 10,800
    proj_kernel<<<(npts + 255) / 256, 256, 0, stream>>>(ref_pts, l2i, proj);
    sample1_kernel<<<npts, 256, 0, stream>>>(feats, proj, samp);
    out_gemm<<<(Bb * Qn) / QT, 256, 0, stream>>>(samp, Wm, bias, out);
}

// Round 3
// 379.170 us; speedup vs baseline: 1.2060x; 1.0011x over previous
//
#include <hip/hip_runtime.h>
#include <cstdint>

#define Bb 2
#define Nc 6
#define Qn 900
#define Cc 256
#define Hc 116
#define Wc 200
#define Pp (Hc * Wc)
#define EPSf 1e-5f

// ---------------- Kernel B: fused project + camera-major bilinear gather ----------------
// One block per (bn, q): consecutive block IDs share one camera plane, so the
// concurrently-resident working set is ~2 planes (~50 MB) << 256 MB L3 —
// duplicate channel-line touches hit L3 instead of re-fetching from HBM
// (verified round 2: −21 µs, matching prediction).
// Projection math is block-uniform (15 FLOPs from scalar loads) — recomputed
// per block instead of a separate kernel + Proj buffer round-trip.
__global__ void sample_kernel(const float* __restrict__ feats,   // (B*N, C, H, W)
                              const float* __restrict__ ref_pts, // (B, Q, 3)
                              const float* __restrict__ l2i,     // (B, N, 4, 4)
                              float* __restrict__ samp) {        // (B*N*Q, C)
    int blk = blockIdx.x;           // bn*Qn + q  (camera-major)
    int c   = threadIdx.x;          // 0..255
    int q   = blk % Qn;
    int bn  = blk / Qn;
    int b   = bn / Nc;
    size_t ob = (size_t)blk * Cc + c;

    // ---- block-uniform projection (all lanes compute identically; scalar loads) ----
    const float* p = ref_pts + ((size_t)b * Qn + q) * 3;
    float px = p[0], py = p[1], pz = p[2];
    const float* M = l2i + (size_t)bn * 16;
    float h0 = M[0]*px + M[1]*py + M[2]*pz  + M[3];
    float h1 = M[4]*px + M[5]*py + M[6]*pz  + M[7];
    float h2 = M[8]*px + M[9]*py + M[10]*pz + M[11];

    float denom = fabsf(h2) + EPSf;
    float x2d = h0 / denom;
    float y2d = h1 / denom;
    // match reference op order: pts / (W-1) * 2 - 1
    float gx = x2d / (float)(Wc - 1) * 2.0f - 1.0f;
    float gy = y2d / (float)(Hc - 1) * 2.0f - 1.0f;
    bool front = h2 > EPSf;
    bool in_img = fmaxf(fabsf(gx), fabsf(gy)) <= 1.0f;

    if (!(front && in_img)) {       // uniform branch
        samp[ob] = 0.0f;
        return;
    }

    // align_corners=False mapping
    float x = ((gx + 1.0f) * (float)Wc - 1.0f) * 0.5f;
    float y = ((gy + 1.0f) * (float)Hc - 1.0f) * 0.5f;
    float x0f = floorf(x), y0f = floorf(y);
    int x0 = (int)x0f, y0 = (int)y0f;
    int x1 = x0 + 1,   y1 = y0 + 1;
    float wx = x - x0f, wy = y - y0f;

    bool vx0 = (x0 >= 0) & (x0 < Wc);
    bool vx1 = (x1 >= 0) & (x1 < Wc);
    bool vy0 = (y0 >= 0) & (y0 < Hc);
    bool vy1 = (y1 >= 0) & (y1 < Hc);
    int cx0 = min(max(x0, 0), Wc - 1);
    int cx1 = min(max(x1, 0), Wc - 1);
    int cy0 = min(max(y0, 0), Hc - 1);
    int cy1 = min(max(y1, 0), Hc - 1);

    const float* img = feats + ((size_t)bn * Cc + c) * (size_t)Pp;
    float v00 = img[cy0 * Wc + cx0] * ((vx0 & vy0) ? 1.0f : 0.0f);
    float v01 = img[cy0 * Wc + cx1] * ((vx1 & vy0) ? 1.0f : 0.0f);
    float v10 = img[cy1 * Wc + cx0] * ((vx0 & vy1) ? 1.0f : 0.0f);
    float v11 = img[cy1 * Wc + cx1] * ((vx1 & vy1) ? 1.0f : 0.0f);

    samp[ob] = (v00 * (1.0f - wx) + v01 * wx) * (1.0f - wy)
             + (v10 * (1.0f - wx) + v11 * wx) * wy;
}

// ---------------- Kernel C: out = mean_n(samp) @ W_out^T + b_out ----------------
// 6-way camera mean folded into the LDS staging loop (coalesced reads).
// QT=4 -> 450 blocks (~2 blocks/CU) for better latency hiding than QT=8's 225.
#define QT 4
__global__ void out_gemm(const float* __restrict__ samp,   // (B*N*Q, C)
                         const float* __restrict__ Wm,     // (C, C) row-major
                         const float* __restrict__ bias,   // (C,)
                         float* __restrict__ out) {        // (B*Q, C)
    __shared__ float sA[QT][Cc];
    int base_q = blockIdx.x * QT;   // row in (B*Q)
    int tid = threadIdx.x;          // 0..255 = co

    #pragma unroll
    for (int i = tid; i < QT * Cc; i += 256) {
        int j = i >> 8;             // Cc == 256
        int c = i & 255;
        int row = base_q + j;
        int b  = row / Qn;
        int qq = row - b * Qn;
        const float* sp = samp + ((size_t)(b * Nc) * Qn + qq) * Cc + c;
        float s = 0.0f;
        #pragma unroll
        for (int n = 0; n < Nc; ++n)
            s += sp[(size_t)n * Qn * Cc];
        sA[j][c] = s * (1.0f / 6.0f);
    }
    __syncthreads();

    float acc[QT];
    #pragma unroll
    for (int j = 0; j < QT; ++j) acc[j] = 0.0f;

    const float4* wrow = (const float4*)(Wm + (size_t)tid * Cc);
    #pragma unroll 4
    for (int c4 = 0; c4 < Cc / 4; ++c4) {
        float4 w = wrow[c4];
        #pragma unroll
        for (int j = 0; j < QT; ++j) {
            acc[j] += w.x * sA[j][4*c4 + 0] + w.y * sA[j][4*c4 + 1]
                    + w.z * sA[j][4*c4 + 2] + w.w * sA[j][4*c4 + 3];
        }
    }
    float bb = bias[tid];
    #pragma unroll
    for (int j = 0; j < QT; ++j)
        out[(size_t)(base_q + j) * Cc + tid] = acc[j] + bb;
}

extern "C" void kernel_launch(void* const* d_in, const int* in_sizes, int n_in,
                              void* d_out, int out_size, void* d_ws, size_t ws_size,
                              hipStream_t stream) {
    // inputs: 0=query (unused), 1=reference_points, 2=image_features, 3=lidar2img, 4=W_out, 5=b_out
    const float* ref_pts = (const float*)d_in[1];
    const float* feats   = (const float*)d_in[2];
    const float* l2i     = (const float*)d_in[3];
    const float* Wm      = (const float*)d_in[4];
    const float* bias    = (const float*)d_in[5];
    float* out = (float*)d_out;

    float* samp = (float*)d_ws;     // (B*N*Q, C) = 11.06 MB

    int npts = Bb * Nc * Qn;        // 10,800 blocks, camera-major
    sample_kernel<<<npts, 256, 0, stream>>>(feats, ref_pts, l2i, samp);
    out_gemm<<<(Bb * Qn) / QT, 256, 0, stream>>>(samp, Wm, bias, out);
}